// Round 1
// baseline (1311.149 us; speedup 1.0000x reference)
//
#include <hip/hip_runtime.h>

// out_i = 0.1 * x_i * sum_j A[i][j] * (1 - x_j)
// n = 16384, A row-major fp32 (1.07 GB), x fp32 [n,1], out fp32 [n,1].
// Memory-bound: A read once. One wave (64 lanes) per row, 4 waves/block.

#define N 16384

__global__ __launch_bounds__(256) void epidemic_matvec(
    const float* __restrict__ x,
    const float* __restrict__ A,
    float* __restrict__ out) {
  const int wave = threadIdx.x >> 6;   // 0..3
  const int lane = threadIdx.x & 63;
  const int row  = blockIdx.x * 4 + wave;

  const float4* __restrict__ Arow = (const float4*)(A + (size_t)row * N);
  const float4* __restrict__ xv   = (const float4*)x;

  // 16384 / 4 = 4096 float4 per row; 64 lanes -> 64 iterations.
  // Two accumulators for a shorter dependent-add chain.
  float acc0 = 0.f, acc1 = 0.f;
#pragma unroll 4
  for (int it = 0; it < 64; it += 2) {
    int i0 = it * 64 + lane;
    int i1 = (it + 1) * 64 + lane;
    float4 a0 = Arow[i0];
    float4 x0 = xv[i0];
    float4 a1 = Arow[i1];
    float4 x1 = xv[i1];
    acc0 += a0.x * (1.f - x0.x) + a0.y * (1.f - x0.y)
          + a0.z * (1.f - x0.z) + a0.w * (1.f - x0.w);
    acc1 += a1.x * (1.f - x1.x) + a1.y * (1.f - x1.y)
          + a1.z * (1.f - x1.z) + a1.w * (1.f - x1.w);
  }
  float acc = acc0 + acc1;

  // 64-wide wave reduction (wave = 64 on CDNA, not 32)
#pragma unroll
  for (int off = 32; off > 0; off >>= 1)
    acc += __shfl_down(acc, off, 64);

  if (lane == 0)
    out[row] = 0.1f * x[row] * acc;
}

extern "C" void kernel_launch(void* const* d_in, const int* in_sizes, int n_in,
                              void* d_out, int out_size, void* d_ws, size_t ws_size,
                              hipStream_t stream) {
  // setup_inputs order: t (1), x (16384), A (16384*16384) -- all fp32
  const float* x = (const float*)d_in[1];
  const float* A = (const float*)d_in[2];
  float* out = (float*)d_out;

  // 16384 rows / 4 rows-per-block = 4096 blocks
  epidemic_matvec<<<N / 4, 256, 0, stream>>>(x, A, out);
}